// Round 6
// baseline (870.339 us; speedup 1.0000x reference)
//
#include <hip/hip_runtime.h>
#include <stdint.h>

typedef unsigned short u16;
typedef unsigned int u32;
typedef __attribute__((ext_vector_type(8))) short bf16x8;   // 8 bf16 (4 VGPRs)
typedef __attribute__((ext_vector_type(4))) float f32x4;    // MFMA C/D

#define G_AS __attribute__((address_space(1)))
#define L_AS __attribute__((address_space(3)))

__device__ __forceinline__ void gload16(const void* g, void* l) {
  __builtin_amdgcn_global_load_lds((const G_AS u32*)g, (L_AS u32*)l, 16, 0, 0);
}

// ---------------- static ragged-group metadata (compile-time) ----------------
// M = {4096,2048,1024,3072,2048,1024,1536,1584}, K=N=2048
// a_off (== c_off) cumulative M*2048 (fp32 elements; also u16 elements of A').

// ============================================================================
// Pipeline path: pair-interleaved k-tile-major layouts + 3-buf gemm5
// A'[g][kt][rp][slot]: kt=k>>5 (64 per row), rp=local_row>>1, 8 slots x 16B.
//   slot = ((r&1)*4 + c32) ^ (rp&7), c32=(k&31)>>3.  128B per rp per kt.
// B'[g][kt][np][slot]: same for B^T rows (np = n>>1), 1024 np per kt.
// Staging a (BM=256,BK=32) A-slice or (BN=128,BK=32) B-slice is then a LINEAR
// global_load_lds copy; fragment ds_reads apply the same XOR -> replicates
// R1's measured-0-conflict pattern (8 slots, 2 lanes each per 16-lane group).
// ============================================================================

__global__ __launch_bounds__(256) void prep2(
    const float* __restrict__ A, u16* __restrict__ Ah, u16* __restrict__ Al,
    const float* __restrict__ B, u16* __restrict__ Bh, u16* __restrict__ Bl) {
  __shared__ float tile[32][256];
  const int cum[9] = {0, 16, 24, 28, 40, 48, 52, 58, 65};
  const int Ms[8] = {4096, 2048, 1024, 3072, 2048, 1024, 1536, 1584};
  const long aoff[8] = {0L, 8388608L, 12582912L, 14680064L,
                        20971520L, 25165824L, 27262976L, 30408704L};
  int bid = blockIdx.x;
  int t = threadIdx.x;
  if (bid < 4160) {
    // ---- A part: one (256-row m-tile, kt) per block; thread t = one row ----
    int mtg = bid >> 6, kt = bid & 63;
    int g = 0;
#pragma unroll
    for (int i = 1; i < 8; ++i) if (mtg >= cum[i]) g = i;
    int m0 = (mtg - cum[g]) << 8;
    int r = m0 + t;
    if (r < Ms[g]) {
      const float* src = A + aoff[g] + (long)r * 2048 + (kt << 5);
      float x[32];
#pragma unroll
      for (int p = 0; p < 8; ++p) {
        float4 v = ((const float4*)src)[p];
        x[4 * p] = v.x; x[4 * p + 1] = v.y; x[4 * p + 2] = v.z; x[4 * p + 3] = v.w;
      }
      int rp = r >> 1;
      long base = aoff[g] + (long)kt * (Ms[g] * 32) + (long)rp * 64;
#pragma unroll
      for (int c = 0; c < 4; ++c) {
        int slot = (((r & 1) << 2) + c) ^ (rp & 7);
        union { u16 u[8]; uint4 v; } H, L;
#pragma unroll
        for (int j = 0; j < 8; ++j) {
          float xv = x[c * 8 + j];
          u32 u = __float_as_uint(xv);
          H.u[j] = (u16)(u >> 16);                              // truncation split
          float rr = xv - __uint_as_float(u & 0xffff0000u);     // exact residual
          L.u[j] = (u16)(__float_as_uint(rr) >> 16);
        }
        *(uint4*)(Ah + base + slot * 8) = H.v;
        *(uint4*)(Al + base + slot * 8) = L.v;
      }
    }
  } else {
    // ---- B part: one (g, kt, 256-col chunk): transpose 32k x 256n ----
    int b2 = bid - 4160;
    int g = b2 >> 9, rem = b2 & 511, kt = rem >> 3, nc = rem & 7;
    const float* Bg = B + (long)g * 4194304L + ((long)(kt << 5)) * 2048 + (nc << 8);
#pragma unroll
    for (int p = 0; p < 8; ++p) {                // coalesced 32x256 load
      int id = (p << 8) + t;
      int kr = id >> 6, c4 = (id & 63) << 2;
      float4 v = *(const float4*)(Bg + (long)kr * 2048 + c4);
      tile[kr][c4] = v.x; tile[kr][c4 + 1] = v.y;
      tile[kr][c4 + 2] = v.z; tile[kr][c4 + 3] = v.w;
    }
    __syncthreads();
    int n = (nc << 8) + t;                       // global col, thread t = one n
    int np = n >> 1;
    float x[32];
#pragma unroll
    for (int kr = 0; kr < 32; ++kr) x[kr] = tile[kr][t];
    long base = (long)g * 4194304L + (long)kt * 65536 + (long)np * 64;
#pragma unroll
    for (int c = 0; c < 4; ++c) {
      int slot = (((n & 1) << 2) + c) ^ (np & 7);
      union { u16 u[8]; uint4 v; } H, L;
#pragma unroll
      for (int j = 0; j < 8; ++j) {
        float xv = x[c * 8 + j];
        u32 u = __float_as_uint(xv);
        H.u[j] = (u16)(u >> 16);
        float rr = xv - __uint_as_float(u & 0xffff0000u);
        L.u[j] = (u16)(__float_as_uint(rr) >> 16);
      }
      *(uint4*)(Bh + base + slot * 8) = H.v;
      *(uint4*)(Bl + base + slot * 8) = L.v;
    }
  }
}

// ---------------- gemm5: 256x128 tile, BK=32, 8 waves, 3-buf counted vmcnt --
// Per wave 64x64 = 4x4 frags of 16x16x32; 3 MFMA per pair (bf16x3).
// Ring of 3 LDS buffers (48KB each); depth-2 prefetch; per tile:
//   STAGE(t+2); vmcnt(12); barrier; ds_read frags; setprio(1) 48 MFMA; barrier.
// vmcnt(12) = 2 tiles x 6 loads/thread in flight => tile t globally complete
// (every wave passes its own vmcnt before the barrier).
__global__ __launch_bounds__(512, 2) void gemm5(
    const u16* __restrict__ Ah, const u16* __restrict__ Al,
    const u16* __restrict__ Bh, const u16* __restrict__ Bl,
    const float* __restrict__ Cin, float* __restrict__ Out,
    const float* __restrict__ alpha, const float* __restrict__ beta) {
  __shared__ u16 lds[73728];   // 3 x 48KB
  const int cum[9] = {0, 16, 24, 28, 40, 48, 52, 58, 65};
  const int Ms[8] = {4096, 2048, 1024, 3072, 2048, 1024, 1536, 1584};
  const long aoff[8] = {0L, 8388608L, 12582912L, 14680064L,
                        20971520L, 25165824L, 27262976L, 30408704L};

  int bid = blockIdx.x;
  int mtg = bid >> 4, nt = bid & 15;
  int g = 0;
#pragma unroll
  for (int i = 1; i < 8; ++i) if (mtg >= cum[i]) g = i;
  int m0 = (mtg - cum[g]) << 8;
  int Mg = Ms[g];
  long Au = aoff[g];
  long Bu = (long)g * 4194304L;
  int Mg32 = Mg * 32;
  int rp0 = m0 >> 1;
  int rpMax = (Mg >> 1) - 1;
  int np0 = nt << 6;

  int t = threadIdx.x;
  int lane = t & 63, wv = t >> 6;
  int wrow = (wv >> 1) << 6;      // 0,64,128,192
  int wcol = (wv & 1) << 6;       // 0,64
  int hi4 = lane >> 4, l15 = lane & 15;

  // staging source offsets (u16), kt term added per stage
  int L0 = t << 3;                // u16 index within region, 8 u16/thread
  int rpl = L0 >> 6;              // 0..63
  int offin = L0 & 63;
  int s0 = rp0 + rpl;       if (s0 > rpMax) s0 = rpMax;          // clamp (g8 tail)
  int s1 = rp0 + 64 + rpl;  if (s1 > rpMax) s1 = rpMax;
  long aSrc0 = Au + (long)s0 * 64 + offin;
  long aSrc1 = Au + (long)s1 * 64 + offin;
  long bSrc  = Bu + (long)(np0 + rpl) * 64 + offin;

  // fragment LDS offsets (u16, region-relative); buffer base added per tile
  int aOff[4], bOff[4];
#pragma unroll
  for (int mi = 0; mi < 4; ++mi) {
    int r = wrow + (mi << 4) + l15;
    int rp = r >> 1;
    int slot = (((r & 1) << 2) + hi4) ^ (rp & 7);
    aOff[mi] = (rp << 6) + (slot << 3);
  }
#pragma unroll
  for (int ni = 0; ni < 4; ++ni) {
    int n = wcol + (ni << 4) + l15;
    int np = n >> 1;
    int slot = (((n & 1) << 2) + hi4) ^ (np & 7);
    bOff[ni] = (np << 6) + (slot << 3);
  }

  f32x4 acc[4][4];
#pragma unroll
  for (int mi = 0; mi < 4; ++mi)
#pragma unroll
    for (int ni = 0; ni < 4; ++ni) acc[mi][ni] = 0;

  // LDS byte map per 48KB buffer: Ah[0,16384) Al[16384,32768) Bh[32768,40960) Bl[40960,49152)
#define STAGE5(st, sb) do {                                        \
    long kA = (long)(st) * Mg32;                                   \
    long kB = ((long)(st)) << 16;                                  \
    char* lb_ = (char*)lds + (sb) * 49152;                         \
    int lB_ = L0 << 1;                                             \
    gload16(Ah + kA + aSrc0, lb_ + lB_);                           \
    gload16(Ah + kA + aSrc1, lb_ + 8192 + lB_);                    \
    gload16(Al + kA + aSrc0, lb_ + 16384 + lB_);                   \
    gload16(Al + kA + aSrc1, lb_ + 24576 + lB_);                   \
    gload16(Bh + kB + bSrc,  lb_ + 32768 + lB_);                   \
    gload16(Bl + kB + bSrc,  lb_ + 40960 + lB_);                   \
  } while (0)

  STAGE5(0, 0);
  STAGE5(1, 1);
  int cb = 0;
  for (int kt2 = 0; kt2 < 64; ++kt2) {
    int st = (kt2 + 2) & 63;            // wrap: restages tile 0/1 at the end (dead buffers)
    int sb = cb + 2; if (sb >= 3) sb -= 3;
    STAGE5(st, sb);
    asm volatile("s_waitcnt vmcnt(12)" ::: "memory");   // tile kt2 complete; 2 tiles in flight
    __builtin_amdgcn_s_barrier();
    __builtin_amdgcn_sched_barrier(0);
    const u16* lb = lds + cb * 24576;
    bf16x8 ah[4], al[4], bh[4], bl[4];
#pragma unroll
    for (int mi = 0; mi < 4; ++mi) ah[mi] = *(const bf16x8*)(lb + aOff[mi]);
#pragma unroll
    for (int mi = 0; mi < 4; ++mi) al[mi] = *(const bf16x8*)(lb + 8192 + aOff[mi]);
#pragma unroll
    for (int ni = 0; ni < 4; ++ni) bh[ni] = *(const bf16x8*)(lb + 16384 + bOff[ni]);
#pragma unroll
    for (int ni = 0; ni < 4; ++ni) bl[ni] = *(const bf16x8*)(lb + 20480 + bOff[ni]);
    __builtin_amdgcn_s_setprio(1);
#pragma unroll
    for (int mi = 0; mi < 4; ++mi)
#pragma unroll
      for (int ni = 0; ni < 4; ++ni) {
        acc[mi][ni] = __builtin_amdgcn_mfma_f32_16x16x32_bf16(ah[mi], bh[ni], acc[mi][ni], 0, 0, 0);
        acc[mi][ni] = __builtin_amdgcn_mfma_f32_16x16x32_bf16(ah[mi], bl[ni], acc[mi][ni], 0, 0, 0);
        acc[mi][ni] = __builtin_amdgcn_mfma_f32_16x16x32_bf16(al[mi], bh[ni], acc[mi][ni], 0, 0, 0);
      }
    __builtin_amdgcn_s_setprio(0);
    __builtin_amdgcn_sched_barrier(0);
    __builtin_amdgcn_s_barrier();       // all waves done reading buf cb -> reusable
    cb = cb + 1; if (cb >= 3) cb -= 3;
  }
#undef STAGE5

  // epilogue: out = alpha*acc + beta*C  (C/D: row = 4*(lane>>4)+j, col = lane&15)
  float alg = alpha[g], beg = beta[g];
  long cb0 = aoff[g] + (long)(nt << 7);
#pragma unroll
  for (int mi = 0; mi < 4; ++mi) {
#pragma unroll
    for (int j = 0; j < 4; ++j) {
      int row = m0 + wrow + (mi << 4) + (hi4 << 2) + j;
      if (row < Mg) {
        long rb = cb0 + (long)row * 2048;
#pragma unroll
        for (int ni = 0; ni < 4; ++ni) {
          long idx = rb + wcol + (ni << 4) + l15;
          Out[idx] = alg * acc[mi][ni][j] + beg * Cin[idx];
        }
      }
    }
  }
}

// ============================================================================
// R1-proven fallback path (mid tier) — unchanged.
// ============================================================================
__global__ __launch_bounds__(256) void prep_fused(
    const float* __restrict__ A, u16* __restrict__ Ah, u16* __restrict__ Al,
    const float* __restrict__ B, u16* __restrict__ Bh, u16* __restrict__ Bl) {
  __shared__ float tile[64][257];
  int bid = blockIdx.x;
  int t = threadIdx.x;
  if (bid < 2048) {
    int g = bid >> 8;
    int tt = bid & 255;
    int tk = tt >> 3, tn = tt & 7;
    long gb = (long)g * 4194304L;
    int k0 = tk << 6, n0 = tn << 8;
#pragma unroll
    for (int i = 0; i < 16; ++i) {
      int chunk = (i << 8) + t;
      int r = chunk >> 6;
      int c4 = (chunk & 63) << 2;
      float4 v = *(const float4*)(B + gb + (long)(k0 + r) * 2048 + n0 + c4);
      tile[r][c4] = v.x; tile[r][c4 + 1] = v.y;
      tile[r][c4 + 2] = v.z; tile[r][c4 + 3] = v.w;
    }
    __syncthreads();
    int c = t & 7;
#pragma unroll
    for (int p = 0; p < 8; ++p) {
      int nl = (t >> 3) + (p << 5);
      int n = n0 + nl;
      union { u16 u[8]; uint4 v; } H, L;
#pragma unroll
      for (int j = 0; j < 8; ++j) {
        float x = tile[(c << 3) + j][nl];
        u32 u = __float_as_uint(x);
        H.u[j] = (u16)(u >> 16);
        float r = x - __uint_as_float(u & 0xffff0000u);
        L.u[j] = (u16)(__float_as_uint(r) >> 16);
      }
      long dest = gb + (long)n * 2048 + k0 + ((long)(c ^ (n & 7)) << 3);
      *(uint4*)(Bh + dest) = H.v;
      *(uint4*)(Bl + dest) = L.v;
    }
  } else {
    long i = (long)(bid - 2048) * 256 + t;
    if (i >= 4206592L) return;
    long base = i << 3;
    long row = base >> 11;
    int k = (int)(base & 2047);
    int cs = ((k >> 3) & 7) ^ ((int)row & 7);
    long dest = (row << 11) + (k & 1984) + (cs << 3);
    const float4* ap = (const float4*)(A + base);
    float4 v0 = ap[0], v1 = ap[1];
    float x[8] = {v0.x, v0.y, v0.z, v0.w, v1.x, v1.y, v1.z, v1.w};
    union { u16 u[8]; uint4 v; } H, L;
#pragma unroll
    for (int e = 0; e < 8; ++e) {
      u32 u = __float_as_uint(x[e]);
      H.u[e] = (u16)(u >> 16);
      float r = x[e] - __uint_as_float(u & 0xffff0000u);
      L.u[e] = (u16)(__float_as_uint(r) >> 16);
    }
    *(uint4*)(Ah + dest) = H.v;
    *(uint4*)(Al + dest) = L.v;
  }
}

template <bool PRE_A>
__global__ __launch_bounds__(256, 2) void gemm3(
    const u16* __restrict__ Ah, const u16* __restrict__ Al, const float* __restrict__ Af,
    const u16* __restrict__ Bh, const u16* __restrict__ Bl,
    const float* __restrict__ Cin, float* __restrict__ Out,
    const float* __restrict__ alpha, const float* __restrict__ beta) {
  const int mt_cum[9] = {0, 32, 48, 56, 80, 96, 104, 116, 129};
  const int Ms[8] = {4096, 2048, 1024, 3072, 2048, 1024, 1536, 1584};
  const long a_off[8] = {0L, 8388608L, 12582912L, 14680064L,
                         20971520L, 25165824L, 27262976L, 30408704L};
  __shared__ u16 lds[32768];
  int bid = blockIdx.x;
  int mtg = bid >> 4, nt = bid & 15;
  int g = 0;
#pragma unroll
  for (int i = 1; i < 8; ++i) if (mtg >= mt_cum[i]) g = i;
  int m0 = (mtg - mt_cum[g]) << 7;
  int Mg = Ms[g];
  long abase = a_off[g];
  long bbase = (long)g * 4194304L + ((long)(nt << 7)) * 2048L;
  int t = threadIdx.x;
  int lane = t & 63, wv = t >> 6;
  int wrow = (wv >> 1) << 6, wcol = (wv & 1) << 6;
  int hi4 = lane >> 4, l15 = lane & 15;
  f32x4 acc[4][4];
#pragma unroll
  for (int mi = 0; mi < 4; ++mi)
#pragma unroll
    for (int ni = 0; ni < 4; ++ni) acc[mi][ni] = 0;
  int srow = t >> 3;
  int schunk = t & 7;
  for (int kt = 0; kt < 32; ++kt) {
    __syncthreads();
    long koff = ((long)kt << 6) + (schunk << 3);
    if constexpr (PRE_A) {
#pragma unroll
      for (int rr = 0; rr < 4; ++rr) {
        int tr = (rr << 5) + srow;
        int ar = m0 + tr; ar = ar < Mg ? ar : (Mg - 1);
        long ga = abase + (long)ar * 2048 + koff;
        long gbb = bbase + (long)tr * 2048 + koff;
        int lo = (rr << 12) + (t << 4);
        gload16(Ah + ga, (char*)lds + lo);
        gload16(Al + ga, (char*)lds + 16384 + lo);
        gload16(Bh + gbb, (char*)lds + 32768 + lo);
        gload16(Bl + gbb, (char*)lds + 49152 + lo);
      }
    } else {
#pragma unroll
      for (int rr = 0; rr < 4; ++rr) {
        int tr = (rr << 5) + srow;
        long gbb = bbase + (long)tr * 2048 + koff;
        int lo = (rr << 12) + (t << 4);
        gload16(Bh + gbb, (char*)lds + 32768 + lo);
        gload16(Bl + gbb, (char*)lds + 49152 + lo);
      }
      int rbase = (t >> 2) & 15;
      int f4 = (t & 3) + ((t >> 6) << 2);
#pragma unroll
      for (int rr = 0; rr < 8; ++rr) {
        int tr = (rr << 4) + rbase;
        int ar = m0 + tr; ar = ar < Mg ? ar : (Mg - 1);
        float4 v = *(const float4*)(Af + abase + (long)ar * 2048 + ((long)kt << 6) + (f4 << 2));
        float x[4] = {v.x, v.y, v.z, v.w};
        union { u16 u[4]; uint2 w; } Hh, Ll;
#pragma unroll
        for (int e = 0; e < 4; ++e) {
          u32 u = __float_as_uint(x[e]);
          Hh.u[e] = (u16)(u >> 16);
          float r = x[e] - __uint_as_float(u & 0xffff0000u);
          Ll.u[e] = (u16)(__float_as_uint(r) >> 16);
        }
        int db = (tr << 7) + (((f4 >> 1) ^ (tr & 7)) << 4) + ((f4 & 1) << 3);
        *(uint2*)((char*)lds + db) = Hh.w;
        *(uint2*)((char*)lds + 16384 + db) = Ll.w;
      }
    }
    __syncthreads();
#pragma unroll
    for (int k2 = 0; k2 < 2; ++k2) {
      int cc = (k2 << 2) + hi4;
      bf16x8 ah[4], al[4], bh[4], bl[4];
#pragma unroll
      for (int mi = 0; mi < 4; ++mi) {
        int r = wrow + (mi << 4) + l15;
        int off = (r << 6) + ((cc ^ (r & 7)) << 3);
        ah[mi] = *(const bf16x8*)(lds + off);
        al[mi] = *(const bf16x8*)(lds + 8192 + off);
      }
#pragma unroll
      for (int ni = 0; ni < 4; ++ni) {
        int r = wcol + (ni << 4) + l15;
        int off = (r << 6) + ((cc ^ (r & 7)) << 3);
        bh[ni] = *(const bf16x8*)(lds + 16384 + off);
        bl[ni] = *(const bf16x8*)(lds + 24576 + off);
      }
#pragma unroll
      for (int mi = 0; mi < 4; ++mi)
#pragma unroll
        for (int ni = 0; ni < 4; ++ni) {
          acc[mi][ni] = __builtin_amdgcn_mfma_f32_16x16x32_bf16(ah[mi], bh[ni], acc[mi][ni], 0, 0, 0);
          acc[mi][ni] = __builtin_amdgcn_mfma_f32_16x16x32_bf16(ah[mi], bl[ni], acc[mi][ni], 0, 0, 0);
          acc[mi][ni] = __builtin_amdgcn_mfma_f32_16x16x32_bf16(al[mi], bh[ni], acc[mi][ni], 0, 0, 0);
        }
    }
  }
  float alg = alpha[g], beg = beta[g];
  long cb = abase + ((long)(nt << 7));
#pragma unroll
  for (int mi = 0; mi < 4; ++mi) {
#pragma unroll
    for (int j = 0; j < 4; ++j) {
      int row = m0 + wrow + (mi << 4) + (hi4 << 2) + j;
      if (row < Mg) {
        long rb = cb + (long)row * 2048;
#pragma unroll
        for (int ni = 0; ni < 4; ++ni) {
          long idx = rb + wcol + (ni << 4) + l15;
          Out[idx] = alg * acc[mi][ni][j] + beg * Cin[idx];
        }
      }
    }
  }
}

__global__ __launch_bounds__(256) void gemm_naive(
    const float* __restrict__ A, const float* __restrict__ B,
    const float* __restrict__ Cin, float* __restrict__ Out,
    const float* __restrict__ alpha, const float* __restrict__ beta) {
  const int mt_cum[9] = {0, 64, 96, 112, 160, 192, 208, 232, 257};
  const int Ms[8] = {4096, 2048, 1024, 3072, 2048, 1024, 1536, 1584};
  const long a_off[8] = {0L, 8388608L, 12582912L, 14680064L,
                         20971520L, 25165824L, 27262976L, 30408704L};
  __shared__ float As[16][65];
  __shared__ float Bs[16][68];
  int bid = blockIdx.x;
  int mtg = bid >> 5, nt = bid & 31;
  int g = 0;
#pragma unroll
  for (int i = 1; i < 8; ++i) if (mtg >= mt_cum[i]) g = i;
  int m0 = (mtg - mt_cum[g]) << 6, n0 = nt << 6;
  int Mg = Ms[g];
  int t = threadIdx.x;
  int ty = t >> 4, tx = t & 15;
  float acc[4][4] = {};
  for (int k0 = 0; k0 < 2048; k0 += 16) {
    __syncthreads();
    {
      int m = t >> 2, ks = (t & 3) << 2;
      int ar = m0 + m; ar = ar < Mg ? ar : (Mg - 1);
      float4 v = *(const float4*)(A + a_off[g] + (long)ar * 2048 + k0 + ks);
      As[ks][m] = v.x; As[ks + 1][m] = v.y; As[ks + 2][m] = v.z; As[ks + 3][m] = v.w;
    }
    {
      int k = t >> 4, n4 = (t & 15) << 2;
      float4 v = *(const float4*)(B + (long)g * 4194304L + (long)(k0 + k) * 2048 + n0 + n4);
      *(float4*)&Bs[k][n4] = v;
    }
    __syncthreads();
#pragma unroll
    for (int k = 0; k < 16; ++k) {
      float a[4], b[4];
#pragma unroll
      for (int i = 0; i < 4; ++i) a[i] = As[k][(ty << 2) + i];
#pragma unroll
      for (int j = 0; j < 4; ++j) b[j] = Bs[k][(tx << 2) + j];
#pragma unroll
      for (int i = 0; i < 4; ++i)
#pragma unroll
        for (int j = 0; j < 4; ++j) acc[i][j] += a[i] * b[j];
    }
  }
  float alg = alpha[g], beg = beta[g];
#pragma unroll
  for (int i = 0; i < 4; ++i) {
    int row = m0 + (ty << 2) + i;
    if (row < Mg) {
#pragma unroll
      for (int j = 0; j < 4; ++j) {
        long idx = a_off[g] + (long)row * 2048 + n0 + (tx << 2) + j;
        Out[idx] = alg * acc[i][j] + beg * Cin[idx];
      }
    }
  }
}

extern "C" void kernel_launch(void* const* d_in, const int* in_sizes, int n_in,
                              void* d_out, int out_size, void* d_ws, size_t ws_size,
                              hipStream_t stream) {
  const float* A = (const float*)d_in[0];
  const float* B = (const float*)d_in[1];
  const float* C = (const float*)d_in[2];
  const float* alpha = (const float*)d_in[3];
  const float* beta = (const float*)d_in[4];
  float* Out = (float*)d_out;

  if (ws_size >= 268828672ull) {
    u16* ws16 = (u16*)d_ws;
    u16* Bh = ws16;                  // 33,554,432 u16
    u16* Bl = ws16 + 33554432;
    u16* Ah = ws16 + 67108864;       // 33,652,736 u16
    u16* Al = ws16 + 100761600;
    prep2<<<8256, 256, 0, stream>>>(A, Ah, Al, B, Bh, Bl);
    gemm5<<<1040, 512, 0, stream>>>(Ah, Al, Bh, Bl, C, Out, alpha, beta);
  } else if (ws_size >= 134217728ull) {
    u16* ws16 = (u16*)d_ws;
    u16* Bh = ws16;
    u16* Bl = ws16 + 33554432;
    prep_fused<<<2048, 256, 0, stream>>>(nullptr, nullptr, nullptr, B, Bh, Bl);
    gemm3<false><<<2064, 256, 0, stream>>>(nullptr, nullptr, A, Bh, Bl, C, Out, alpha, beta);
  } else {
    gemm_naive<<<8224, 256, 0, stream>>>(A, B, C, Out, alpha, beta);
  }
}